// Round 1
// baseline (23437.291 us; speedup 1.0000x reference)
//
#include <hip/hip_runtime.h>
#include <cstdint>
#include <cstddef>

#define HID    768
#define EMB    512
#define SEQ    256
#define BATCH  64
#define G4     3072                 // 4*HID
#define XZ_TSTRIDE 196608           // G4*BATCH
#define TB_STRIDE  49152            // BATCH*HID
#define GSTRIDE    12582912         // SEQ*BATCH*HID

__device__ __forceinline__ float bf2f(unsigned int u16) {
    union { unsigned int u; float f; } v; v.u = u16 << 16; return v.f;
}
__device__ __forceinline__ unsigned short f2bf(float f) {
    union { float f; unsigned int u; } v; v.f = f;
    return (unsigned short)((v.u + 0x7FFFu + ((v.u >> 16) & 1u)) >> 16);
}
__device__ __forceinline__ float sigm(float x) { return 1.0f / (1.0f + __expf(-x)); }
__device__ __forceinline__ float tanh_(float x) { return 2.0f / (1.0f + __expf(-2.0f * x)) - 1.0f; }

// ---------------------------------------------------------------------------
// Kernel A: Xz[t][j][b] = emb[tok[b][t]] . W_ih[j] + b_ih[j] + b_hh[j]
// C[M=16384][N=3072] = A[M,512] * W^T ; m = t*64 + b ; stored transposed per t-slab.
// 128x128 tile, 256 threads, 8x8 per thread, BK=16.
// ---------------------------------------------------------------------------
__global__ __launch_bounds__(256) void gemm_xz(
    const int* __restrict__ tok, const float* __restrict__ emb,
    const float* __restrict__ Wih, const float* __restrict__ bih,
    const float* __restrict__ bhh, float* __restrict__ Xz)
{
    __shared__ float As[16][128];
    __shared__ float Bs[16][128];

    const int tid = threadIdx.x;
    const int tx = tid & 15;          // 16 col-threads
    const int ty = tid >> 4;          // 16 row-threads
    const int n0 = blockIdx.x * 128;
    const int m0 = blockIdx.y * 128;

    // staging assignment: each thread stages half a row (8 floats) of A and B
    const int smm   = tid >> 1;       // 0..127
    const int shalf = tid & 1;        // 0..1
    const int sm = m0 + smm;
    const int st = sm >> 6;
    const int sb = sm & 63;
    const int stok = tok[sb * SEQ + st];
    const float* __restrict__ arow = emb + (size_t)stok * EMB;
    const float* __restrict__ brow = Wih + (size_t)(n0 + smm) * EMB;

    float acc[8][8];
    #pragma unroll
    for (int r = 0; r < 8; ++r)
        #pragma unroll
        for (int s = 0; s < 8; ++s) acc[r][s] = 0.0f;

    for (int k0 = 0; k0 < EMB; k0 += 16) {
        const float4 a0 = *(const float4*)(arow + k0 + shalf * 8);
        const float4 a1 = *(const float4*)(arow + k0 + shalf * 8 + 4);
        const float4 c0 = *(const float4*)(brow + k0 + shalf * 8);
        const float4 c1 = *(const float4*)(brow + k0 + shalf * 8 + 4);
        __syncthreads();
        const int kb = shalf * 8;
        As[kb + 0][smm] = a0.x; As[kb + 1][smm] = a0.y;
        As[kb + 2][smm] = a0.z; As[kb + 3][smm] = a0.w;
        As[kb + 4][smm] = a1.x; As[kb + 5][smm] = a1.y;
        As[kb + 6][smm] = a1.z; As[kb + 7][smm] = a1.w;
        Bs[kb + 0][smm] = c0.x; Bs[kb + 1][smm] = c0.y;
        Bs[kb + 2][smm] = c0.z; Bs[kb + 3][smm] = c0.w;
        Bs[kb + 4][smm] = c1.x; Bs[kb + 5][smm] = c1.y;
        Bs[kb + 6][smm] = c1.z; Bs[kb + 7][smm] = c1.w;
        __syncthreads();

        #pragma unroll
        for (int kk = 0; kk < 16; ++kk) {
            float av[8], bv[8];
            *(float4*)&av[0] = *(const float4*)&As[kk][ty * 8];
            *(float4*)&av[4] = *(const float4*)&As[kk][ty * 8 + 4];
            *(float4*)&bv[0] = *(const float4*)&Bs[kk][tx * 8];
            *(float4*)&bv[4] = *(const float4*)&Bs[kk][tx * 8 + 4];
            #pragma unroll
            for (int r = 0; r < 8; ++r)
                #pragma unroll
                for (int s = 0; s < 8; ++s)
                    acc[r][s] += av[r] * bv[s];
        }
    }

    // store transposed: Xz[tt*196608 + j*64 + bb]
    #pragma unroll
    for (int s = 0; s < 8; ++s) {
        const int j = n0 + tx * 8 + s;
        const float bias = bih[j] + bhh[j];
        #pragma unroll
        for (int r = 0; r < 8; ++r) {
            const int mm = ty * 8 + r;
            const int m = m0 + mm;
            const int tt = m >> 6;
            const int bb = m & 63;
            Xz[(size_t)tt * XZ_TSTRIDE + (size_t)j * 64 + bb] = acc[r][s] + bias;
        }
    }
}

// ---------------------------------------------------------------------------
// Kernel B: one LSTM timestep.
// 384 blocks x 256 threads. Block = 16 n x 8 b, k-split 2.
// thread: nn = tid&15, bb = (tid>>4)&7, kh = tid>>7
// h state: bf16 [b][k]; c state: f32 [b][n].
// ---------------------------------------------------------------------------
__global__ __launch_bounds__(256) void lstm_step(
    const int t,
    const float* __restrict__ Xz, const float* __restrict__ Whh,
    const unsigned short* __restrict__ h_in, unsigned short* __restrict__ h_out,
    float* __restrict__ c_st,
    float* __restrict__ outg, float* __restrict__ outf,
    float* __restrict__ outi, float* __restrict__ outo)
{
    __shared__ float part[8][16][4];

    const int tid = threadIdx.x;
    const int nn = tid & 15;
    const int bb = (tid >> 4) & 7;
    const int kh = tid >> 7;
    const int n = (blockIdx.x % 48) * 16 + nn;
    const int b = (blockIdx.x / 48) * 8 + bb;

    float a0 = 0.f, a1 = 0.f, a2 = 0.f, a3 = 0.f;

    if (t > 0) {
        const unsigned short* __restrict__ hr = h_in + b * HID + kh * 384;
        const float* __restrict__ w0 = Whh + (size_t)n * HID + kh * 384;
        const float* __restrict__ w1 = w0 + (size_t)HID * HID;
        const float* __restrict__ w2 = w1 + (size_t)HID * HID;
        const float* __restrict__ w3 = w2 + (size_t)HID * HID;
        #pragma unroll 4
        for (int k = 0; k < 384; k += 8) {
            const uint4 hu = *(const uint4*)(hr + k);
            const float h0 = bf2f(hu.x & 0xFFFFu), h1v = bf2f(hu.x >> 16);
            const float h2 = bf2f(hu.y & 0xFFFFu), h3v = bf2f(hu.y >> 16);
            const float h4 = bf2f(hu.z & 0xFFFFu), h5v = bf2f(hu.z >> 16);
            const float h6 = bf2f(hu.w & 0xFFFFu), h7v = bf2f(hu.w >> 16);
            float4 p, q;
            p = *(const float4*)(w0 + k); q = *(const float4*)(w0 + k + 4);
            a0 += h0*p.x + h1v*p.y + h2*p.z + h3v*p.w + h4*q.x + h5v*q.y + h6*q.z + h7v*q.w;
            p = *(const float4*)(w1 + k); q = *(const float4*)(w1 + k + 4);
            a1 += h0*p.x + h1v*p.y + h2*p.z + h3v*p.w + h4*q.x + h5v*q.y + h6*q.z + h7v*q.w;
            p = *(const float4*)(w2 + k); q = *(const float4*)(w2 + k + 4);
            a2 += h0*p.x + h1v*p.y + h2*p.z + h3v*p.w + h4*q.x + h5v*q.y + h6*q.z + h7v*q.w;
            p = *(const float4*)(w3 + k); q = *(const float4*)(w3 + k + 4);
            a3 += h0*p.x + h1v*p.y + h2*p.z + h3v*p.w + h4*q.x + h5v*q.y + h6*q.z + h7v*q.w;
        }
    }

    if (kh == 1) {
        part[bb][nn][0] = a0; part[bb][nn][1] = a1;
        part[bb][nn][2] = a2; part[bb][nn][3] = a3;
    }
    __syncthreads();

    if (kh == 0) {
        a0 += part[bb][nn][0]; a1 += part[bb][nn][1];
        a2 += part[bb][nn][2]; a3 += part[bb][nn][3];

        const size_t xb = (size_t)t * XZ_TSTRIDE + (size_t)n * 64 + b;
        a0 += Xz[xb];                 // i  (rows 0..H)
        a1 += Xz[xb + 49152];         // f  (rows H..2H)
        a2 += Xz[xb + 2 * 49152];     // g  (rows 2H..3H)
        a3 += Xz[xb + 3 * 49152];     // o  (rows 3H..4H)

        const float iG = sigm(a0);
        const float fG = sigm(a1);
        const float gG = tanh_(a2);
        const float oG = sigm(a3);

        const int cn = b * HID + n;
        const float c_old = (t > 0) ? c_st[cn] : 0.0f;
        const float cN = fG * c_old + iG * gG;
        const float hN = oG * tanh_(cN);
        c_st[cn] = cN;
        h_out[cn] = f2bf(hN);

        const size_t gi = (size_t)t * TB_STRIDE + (size_t)cn;
        outg[gi] = gG;   // output order: g, f, i, o
        outf[gi] = fG;
        outi[gi] = iG;
        outo[gi] = oG;
    }
}

// ---------------------------------------------------------------------------
// Kernel C: logits[b][cls] = hT[b] . W_cls[cls] + b_cls[cls]
// ---------------------------------------------------------------------------
__global__ void logits_k(const unsigned short* __restrict__ hT,
                         const float* __restrict__ Wcls,
                         const float* __restrict__ bcls,
                         float* __restrict__ out)
{
    const int tid = threadIdx.x;          // 128 threads
    const int b = tid >> 1, cls = tid & 1;
    float acc = bcls[cls];
    const unsigned short* __restrict__ hr = hT + b * HID;
    const float* __restrict__ wr = Wcls + cls * HID;
    for (int k = 0; k < HID; ++k) acc += bf2f(hr[k]) * wr[k];
    out[b * 2 + cls] = acc;
}

// ---------------------------------------------------------------------------
extern "C" void kernel_launch(void* const* d_in, const int* in_sizes, int n_in,
                              void* d_out, int out_size, void* d_ws, size_t ws_size,
                              hipStream_t stream)
{
    const int*   tok  = (const int*)d_in[0];
    const float* emb  = (const float*)d_in[1];
    const float* Wih  = (const float*)d_in[2];
    const float* Whh  = (const float*)d_in[3];
    const float* bih  = (const float*)d_in[4];
    const float* bhh  = (const float*)d_in[5];
    const float* Wcls = (const float*)d_in[6];
    const float* bcls = (const float*)d_in[7];
    float* out = (float*)d_out;

    char* ws = (char*)d_ws;
    float* Xz = (float*)ws;                                          // 201,326,592 B
    unsigned short* hA = (unsigned short*)(ws + 201326592);          // 98,304 B
    unsigned short* hB = (unsigned short*)(ws + 201326592 + 98304);  // 98,304 B
    float* c_st = (float*)(ws + 201326592 + 196608);                 // 196,608 B

    float* out_log = out;             // [64,2]
    float* out_g = out + 128;
    float* out_f = out_g + GSTRIDE;
    float* out_i = out_f + GSTRIDE;
    float* out_o = out_i + GSTRIDE;

    gemm_xz<<<dim3(24, 128), 256, 0, stream>>>(tok, emb, Wih, bih, bhh, Xz);

    for (int t = 0; t < SEQ; ++t) {
        unsigned short* ho = (t & 1) ? hB : hA;
        const unsigned short* hi = (t & 1) ? hA : hB;
        lstm_step<<<384, 256, 0, stream>>>(t, Xz, Whh, hi, ho, c_st,
                                           out_g, out_f, out_i, out_o);
    }

    logits_k<<<1, 128, 0, stream>>>(hB, Wcls, bcls, out_log);
}

// Round 2
// 3975.708 us; speedup vs baseline: 5.8951x; 5.8951x over previous
//
#include <hip/hip_runtime.h>
#include <cstdint>
#include <cstddef>

#define HID    768
#define EMB    512
#define SEQ    256
#define BATCH  64
#define G4     3072
#define XZ_TSTRIDE 196608           // G4*BATCH
#define TB_STRIDE  49152            // BATCH*HID
#define GSTRIDE    12582912         // SEQ*BATCH*HID
#define NB     96                   // persistent blocks (1 per CU, co-resident)
#define UB     8                    // hidden units per block

typedef __attribute__((ext_vector_type(8))) short bf16x8;
typedef __attribute__((ext_vector_type(4))) float f32x4;

__device__ __forceinline__ float bf2f(unsigned int u16) {
    union { unsigned int u; float f; } v; v.u = u16 << 16; return v.f;
}
__device__ __forceinline__ unsigned short f2bf(float f) {
    union { float f; unsigned int u; } v; v.f = f;
    return (unsigned short)((v.u + 0x7FFFu + ((v.u >> 16) & 1u)) >> 16);
}
__device__ __forceinline__ float sigm(float x) { return 1.0f / (1.0f + __expf(-x)); }
__device__ __forceinline__ float tanh_(float x) { return 2.0f / (1.0f + __expf(-2.0f * x)) - 1.0f; }

// XOR swizzle: spread 8 consecutive rows (stride 1536B) over 8 distinct 16B
// slots. Pure function of the linear byte address -> writer/reader symmetric.
__device__ __forceinline__ unsigned swz(unsigned lin) {
    return lin ^ (((lin >> 9) & 7u) << 4);
}

// ---------------------------------------------------------------------------
// Kernel A (unchanged from round 1, verified): Xz[t][j][b]
// ---------------------------------------------------------------------------
__global__ __launch_bounds__(256) void gemm_xz(
    const int* __restrict__ tok, const float* __restrict__ emb,
    const float* __restrict__ Wih, const float* __restrict__ bih,
    const float* __restrict__ bhh, float* __restrict__ Xz)
{
    __shared__ float As[16][128];
    __shared__ float Bs[16][128];

    const int tid = threadIdx.x;
    const int tx = tid & 15;
    const int ty = tid >> 4;
    const int n0 = blockIdx.x * 128;
    const int m0 = blockIdx.y * 128;

    const int smm   = tid >> 1;
    const int shalf = tid & 1;
    const int sm = m0 + smm;
    const int st = sm >> 6;
    const int sb = sm & 63;
    const int stok = tok[sb * SEQ + st];
    const float* __restrict__ arow = emb + (size_t)stok * EMB;
    const float* __restrict__ brow = Wih + (size_t)(n0 + smm) * EMB;

    float acc[8][8];
    #pragma unroll
    for (int r = 0; r < 8; ++r)
        #pragma unroll
        for (int s = 0; s < 8; ++s) acc[r][s] = 0.0f;

    for (int k0 = 0; k0 < EMB; k0 += 16) {
        const float4 a0 = *(const float4*)(arow + k0 + shalf * 8);
        const float4 a1 = *(const float4*)(arow + k0 + shalf * 8 + 4);
        const float4 c0 = *(const float4*)(brow + k0 + shalf * 8);
        const float4 c1 = *(const float4*)(brow + k0 + shalf * 8 + 4);
        __syncthreads();
        const int kb = shalf * 8;
        As[kb + 0][smm] = a0.x; As[kb + 1][smm] = a0.y;
        As[kb + 2][smm] = a0.z; As[kb + 3][smm] = a0.w;
        As[kb + 4][smm] = a1.x; As[kb + 5][smm] = a1.y;
        As[kb + 6][smm] = a1.z; As[kb + 7][smm] = a1.w;
        Bs[kb + 0][smm] = c0.x; Bs[kb + 1][smm] = c0.y;
        Bs[kb + 2][smm] = c0.z; Bs[kb + 3][smm] = c0.w;
        Bs[kb + 4][smm] = c1.x; Bs[kb + 5][smm] = c1.y;
        Bs[kb + 6][smm] = c1.z; Bs[kb + 7][smm] = c1.w;
        __syncthreads();

        #pragma unroll
        for (int kk = 0; kk < 16; ++kk) {
            float av[8], bv[8];
            *(float4*)&av[0] = *(const float4*)&As[kk][ty * 8];
            *(float4*)&av[4] = *(const float4*)&As[kk][ty * 8 + 4];
            *(float4*)&bv[0] = *(const float4*)&Bs[kk][tx * 8];
            *(float4*)&bv[4] = *(const float4*)&Bs[kk][tx * 8 + 4];
            #pragma unroll
            for (int r = 0; r < 8; ++r)
                #pragma unroll
                for (int s = 0; s < 8; ++s)
                    acc[r][s] += av[r] * bv[s];
        }
    }

    #pragma unroll
    for (int s = 0; s < 8; ++s) {
        const int j = n0 + tx * 8 + s;
        const float bias = bih[j] + bhh[j];
        #pragma unroll
        for (int r = 0; r < 8; ++r) {
            const int mm = ty * 8 + r;
            const int m = m0 + mm;
            const int tt = m >> 6;
            const int bb = m & 63;
            Xz[(size_t)tt * XZ_TSTRIDE + (size_t)j * 64 + bb] = acc[r][s] + bias;
        }
    }
}

// ---------------------------------------------------------------------------
// Kernel B: PERSISTENT recurrence. 96 blocks x 256 threads (4 waves), one
// block per CU, all co-resident. Each block owns UB=8 hidden units and their
// 4 gate columns (32 packed z-cols). bf16 W_hh slice lives in LDS for the
// whole kernel; h ping-pongs through global bf16 buffers; c stays in regs.
// Packed col c: gate G = c>>3 within tile pair, unit u = c&7.
//   tile0 (cols 0..15):  G0 = c>>3 in {0:i, 1:f}   (both sigmoid)
//   tile1 (cols 16..31): G1 = 2 + ((c>>3)&1) in {2:g(tanh), 3:o(sigmoid)}
// z-row R(c) = G*768 + j0 + u  (reference split order i,f,g,o).
// ---------------------------------------------------------------------------
__global__ __launch_bounds__(256, 1) void lstm_persist(
    const float* __restrict__ Xz, const float* __restrict__ Whh,
    unsigned short* __restrict__ hbuf0, unsigned short* __restrict__ hbuf1,
    int* __restrict__ bar,
    float* __restrict__ outg, float* __restrict__ outf,
    float* __restrict__ outi, float* __restrict__ outo)
{
    __shared__ uint4 Wl4[3072];   // 32 rows x 768 bf16, swizzled  (48 KB)
    __shared__ uint4 Hl4[6144];   // 64 rows x 768 bf16, swizzled  (96 KB)
    char* const Wl = (char*)Wl4;
    char* const Hl = (char*)Hl4;

    const int tid  = threadIdx.x;
    const int lane = tid & 63;
    const int w    = tid >> 6;          // wave id: M-tile (batch rows 16w..16w+15)
    const int j0   = blockIdx.x * UB;

    // ---- one-time: W_hh slice -> bf16 -> LDS (swizzled) --------------------
    for (int idx = tid; idx < 3072; idx += 256) {
        const int c  = idx / 96;               // packed col 0..31
        const int kc = (idx % 96) * 8;         // element offset in row
        const int R  = (c >> 3) * HID + j0 + (c & 7);
        const float* src = Whh + (size_t)R * HID + kc;
        const float4 f0 = *(const float4*)src;
        const float4 f1 = *(const float4*)(src + 4);
        uint4 pk;
        pk.x = (unsigned)f2bf(f0.x) | ((unsigned)f2bf(f0.y) << 16);
        pk.y = (unsigned)f2bf(f0.z) | ((unsigned)f2bf(f0.w) << 16);
        pk.z = (unsigned)f2bf(f1.x) | ((unsigned)f2bf(f1.y) << 16);
        pk.w = (unsigned)f2bf(f1.z) | ((unsigned)f2bf(f1.w) << 16);
        *(uint4*)(Wl + swz((unsigned)(c * 1536 + kc * 2))) = pk;
    }

    // ---- per-lane constants ------------------------------------------------
    const int col   = lane & 15;        // packed col within tile
    const int u     = col & 7;          // unit within block
    const int gsel  = col >> 3;         // 0 or 1 (which gate of the pair)
    const int rbase = w * 16 + (lane >> 4) * 4;   // batch row of acc reg 0

    // fragment LDS byte addresses (pre-swizzle linear parts)
    const unsigned kbl  = (unsigned)((lane >> 4) * 16);
    const unsigned aLin = (unsigned)((w * 16 + col) * 1536) + kbl;
    const unsigned b0Lin = (unsigned)(col * 1536) + kbl;
    const unsigned b1Lin = (unsigned)((16 + col) * 1536) + kbl;

    // output stream pointers for this lane
    float* const p0 = gsel ? outf : outi;
    float* const p1 = gsel ? outo : outg;
    const size_t xzR0 = (size_t)(gsel * HID + j0 + u) * 64;
    const size_t xzR1 = (size_t)((2 + gsel) * HID + j0 + u) * 64;

    float cReg[4] = {0.f, 0.f, 0.f, 0.f};

    for (int t = 0; t < SEQ; ++t) {
        // ---- prefetch Xz for this step (consumed in epilogue) -------------
        const size_t xzb = (size_t)t * XZ_TSTRIDE + (size_t)rbase;
        const f32x4 xz0 = *(const f32x4*)(Xz + xzb + xzR0);
        const f32x4 xz1 = *(const f32x4*)(Xz + xzb + xzR1);

        // ---- stage h(t-1) -> LDS (bf16, swizzled) -------------------------
        if (t > 0) {
            const unsigned short* hin = (t & 1) ? hbuf0 : hbuf1;
            #pragma unroll 8
            for (int it = 0; it < 24; ++it) {
                const int idx = tid + it * 256;          // 16B chunk 0..6143
                const int row = idx / 96;
                const int kb  = (idx % 96) * 16;
                const uint4 v = *(const uint4*)(hin + (size_t)idx * 8);
                *(uint4*)(Hl + swz((unsigned)(row * 1536 + kb))) = v;
            }
        } else {
            const uint4 zz = {0u, 0u, 0u, 0u};
            #pragma unroll 8
            for (int it = 0; it < 24; ++it) {
                const int idx = tid + it * 256;
                const int row = idx / 96;
                const int kb  = (idx % 96) * 16;
                *(uint4*)(Hl + swz((unsigned)(row * 1536 + kb))) = zz;
            }
        }
        __syncthreads();

        // ---- z_hh = h . Whh^T via MFMA ------------------------------------
        f32x4 acc0 = {0.f, 0.f, 0.f, 0.f};
        f32x4 acc1 = {0.f, 0.f, 0.f, 0.f};
        #pragma unroll 8
        for (int ks = 0; ks < 24; ++ks) {
            const bf16x8 af = *(const bf16x8*)(Hl + swz(aLin + ks * 64));
            const bf16x8 b0 = *(const bf16x8*)(Wl + swz(b0Lin + ks * 64));
            const bf16x8 b1 = *(const bf16x8*)(Wl + swz(b1Lin + ks * 64));
            acc0 = __builtin_amdgcn_mfma_f32_16x16x32_bf16(af, b0, acc0, 0, 0, 0);
            acc1 = __builtin_amdgcn_mfma_f32_16x16x32_bf16(af, b1, acc1, 0, 0, 0);
        }

        // ---- epilogue: gates, outputs, h/c update -------------------------
        float v0[4], v1[4];
        #pragma unroll
        for (int r = 0; r < 4; ++r) {
            const float z0 = acc0[r] + xz0[r];
            const float z1 = acc1[r] + xz1[r];
            v0[r] = sigm(z0);                          // i or f
            v1[r] = gsel ? sigm(z1) : tanh_(z1);       // o or g
        }

        const size_t ob = (size_t)t * TB_STRIDE + (size_t)rbase * HID + (size_t)(j0 + u);
        #pragma unroll
        for (int r = 0; r < 4; ++r) {
            p0[ob + (size_t)r * HID] = v0[r];
            p1[ob + (size_t)r * HID] = v1[r];
        }

        unsigned short* hout = (t & 1) ? hbuf1 : hbuf0;
        #pragma unroll
        for (int r = 0; r < 4; ++r) {
            const float pr0 = __shfl_xor(v0[r], 8);    // partner: f (for low lanes)
            const float pr1 = __shfl_xor(v1[r], 8);    // partner: o (for low lanes)
            if (gsel == 0) {                           // low lanes own (b, unit u)
                const float cN = pr0 * cReg[r] + v0[r] * v1[r];   // f*c + i*g
                cReg[r] = cN;
                hout[(size_t)(rbase + r) * HID + (size_t)(j0 + u)] = f2bf(pr1 * tanh_(cN));
            }
        }

        // ---- grid barrier (agent-scope, XCD-coherence-safe) ---------------
        __syncthreads();                    // all waves' h stores issued
        if (tid == 0) {
            const int old = __hip_atomic_fetch_add(&bar[0], 1, __ATOMIC_ACQ_REL,
                                                   __HIP_MEMORY_SCOPE_AGENT);
            if (old == NB * (t + 1) - 1) {
                __hip_atomic_store(&bar[1], t + 1, __ATOMIC_RELEASE,
                                   __HIP_MEMORY_SCOPE_AGENT);
            } else {
                while (__hip_atomic_load(&bar[1], __ATOMIC_RELAXED,
                                         __HIP_MEMORY_SCOPE_AGENT) <= t)
                    __builtin_amdgcn_s_sleep(2);
            }
            __threadfence();                // acquire: invalidate stale caches
        }
        __syncthreads();
    }
}

// ---------------------------------------------------------------------------
// Kernel C: logits (unchanged)
// ---------------------------------------------------------------------------
__global__ void logits_k(const unsigned short* __restrict__ hT,
                         const float* __restrict__ Wcls,
                         const float* __restrict__ bcls,
                         float* __restrict__ out)
{
    const int tid = threadIdx.x;          // 128 threads
    const int b = tid >> 1, cls = tid & 1;
    float acc = bcls[cls];
    const unsigned short* __restrict__ hr = hT + b * HID;
    const float* __restrict__ wr = Wcls + cls * HID;
    for (int k = 0; k < HID; ++k) acc += bf2f(hr[k]) * wr[k];
    out[b * 2 + cls] = acc;
}

// ---------------------------------------------------------------------------
extern "C" void kernel_launch(void* const* d_in, const int* in_sizes, int n_in,
                              void* d_out, int out_size, void* d_ws, size_t ws_size,
                              hipStream_t stream)
{
    const int*   tok  = (const int*)d_in[0];
    const float* emb  = (const float*)d_in[1];
    const float* Wih  = (const float*)d_in[2];
    const float* Whh  = (const float*)d_in[3];
    const float* bih  = (const float*)d_in[4];
    const float* bhh  = (const float*)d_in[5];
    const float* Wcls = (const float*)d_in[6];
    const float* bcls = (const float*)d_in[7];
    float* out = (float*)d_out;

    char* ws = (char*)d_ws;
    float* Xz = (float*)ws;                                          // 201,326,592 B
    unsigned short* hbuf0 = (unsigned short*)(ws + 201326592);       // 98,304 B
    unsigned short* hbuf1 = (unsigned short*)(ws + 201326592 + 98304);
    int* bar = (int*)(ws + 201326592 + 196608);                      // barrier state

    float* out_log = out;             // [64,2]
    float* out_g = out + 128;
    float* out_f = out_g + GSTRIDE;
    float* out_i = out_f + GSTRIDE;
    float* out_o = out_i + GSTRIDE;

    hipMemsetAsync(bar, 0, 256, stream);

    gemm_xz<<<dim3(24, 128), 256, 0, stream>>>(tok, emb, Wih, bih, bhh, Xz);

    lstm_persist<<<NB, 256, 0, stream>>>(Xz, Whh, hbuf0, hbuf1, bar,
                                         out_g, out_f, out_i, out_o);

    // h(255) lives in hbuf[255&1] = hbuf1
    logits_k<<<1, 128, 0, stream>>>(hbuf1, Wcls, bcls, out_log);
}

// Round 3
// 2419.685 us; speedup vs baseline: 9.6861x; 1.6431x over previous
//
#include <hip/hip_runtime.h>
#include <cstdint>
#include <cstddef>

#define HID    768
#define EMB    512
#define SEQ    256
#define BATCH  64
#define G4     3072
#define XZ_TSTRIDE 196608           // G4*BATCH
#define TB_STRIDE  49152            // BATCH*HID
#define GSTRIDE    12582912         // SEQ*BATCH*HID
#define NB     96                   // persistent blocks
#define UB     8                    // hidden units per block

// ws layout (bytes)
#define HSEQ_OFF   201326592u                      // after Xz (f32)
#define HSEQ_BYTES 25165824u                       // SEQ * BATCH*HID * 2 (bf16)
#define FLAGS_OFF  (HSEQ_OFF + HSEQ_BYTES)         // 226492416
#define FLAGS_BYTES (SEQ * 128 * 4)                // 131072  (96 used + pad per step)

typedef __attribute__((ext_vector_type(8))) short bf16x8;
typedef __attribute__((ext_vector_type(4))) float f32x4;
typedef __attribute__((ext_vector_type(4))) unsigned int u32x4;

__device__ __forceinline__ float bf2f(unsigned int u16) {
    union { unsigned int u; float f; } v; v.u = u16 << 16; return v.f;
}
__device__ __forceinline__ unsigned short f2bf(float f) {
    union { float f; unsigned int u; } v; v.f = f;
    return (unsigned short)((v.u + 0x7FFFu + ((v.u >> 16) & 1u)) >> 16);
}
__device__ __forceinline__ float sigm(float x) { return 1.0f / (1.0f + __expf(-x)); }
__device__ __forceinline__ float tanh_(float x) { return 2.0f / (1.0f + __expf(-2.0f * x)) - 1.0f; }

__device__ __forceinline__ unsigned swz(unsigned lin) {
    return lin ^ (((lin >> 9) & 7u) << 4);
}

// --- cache-bypassing (coherence-point) accessors --------------------------
__device__ __forceinline__ void store16_sys(void* p, u32x4 v) {
    asm volatile("global_store_dwordx4 %0, %1, off sc0 sc1" :: "v"(p), "v"(v) : "memory");
}
__device__ __forceinline__ void store4_sys(int* p, int v) {
    asm volatile("global_store_dword %0, %1, off sc0 sc1" :: "v"(p), "v"(v) : "memory");
}
__device__ __forceinline__ u32x4 load16_sys(const void* p) {
    u32x4 r;
    asm volatile("global_load_dwordx4 %0, %1, off sc0 sc1\n\ts_waitcnt vmcnt(0)"
                 : "=v"(r) : "v"(p) : "memory");
    return r;
}

// ---------------------------------------------------------------------------
// Kernel A (unchanged, verified): Xz[t][j][b]
// ---------------------------------------------------------------------------
__global__ __launch_bounds__(256) void gemm_xz(
    const int* __restrict__ tok, const float* __restrict__ emb,
    const float* __restrict__ Wih, const float* __restrict__ bih,
    const float* __restrict__ bhh, float* __restrict__ Xz)
{
    __shared__ float As[16][128];
    __shared__ float Bs[16][128];

    const int tid = threadIdx.x;
    const int tx = tid & 15;
    const int ty = tid >> 4;
    const int n0 = blockIdx.x * 128;
    const int m0 = blockIdx.y * 128;

    const int smm   = tid >> 1;
    const int shalf = tid & 1;
    const int sm = m0 + smm;
    const int st = sm >> 6;
    const int sb = sm & 63;
    const int stok = tok[sb * SEQ + st];
    const float* __restrict__ arow = emb + (size_t)stok * EMB;
    const float* __restrict__ brow = Wih + (size_t)(n0 + smm) * EMB;

    float acc[8][8];
    #pragma unroll
    for (int r = 0; r < 8; ++r)
        #pragma unroll
        for (int s = 0; s < 8; ++s) acc[r][s] = 0.0f;

    for (int k0 = 0; k0 < EMB; k0 += 16) {
        const float4 a0 = *(const float4*)(arow + k0 + shalf * 8);
        const float4 a1 = *(const float4*)(arow + k0 + shalf * 8 + 4);
        const float4 c0 = *(const float4*)(brow + k0 + shalf * 8);
        const float4 c1 = *(const float4*)(brow + k0 + shalf * 8 + 4);
        __syncthreads();
        const int kb = shalf * 8;
        As[kb + 0][smm] = a0.x; As[kb + 1][smm] = a0.y;
        As[kb + 2][smm] = a0.z; As[kb + 3][smm] = a0.w;
        As[kb + 4][smm] = a1.x; As[kb + 5][smm] = a1.y;
        As[kb + 6][smm] = a1.z; As[kb + 7][smm] = a1.w;
        Bs[kb + 0][smm] = c0.x; Bs[kb + 1][smm] = c0.y;
        Bs[kb + 2][smm] = c0.z; Bs[kb + 3][smm] = c0.w;
        Bs[kb + 4][smm] = c1.x; Bs[kb + 5][smm] = c1.y;
        Bs[kb + 6][smm] = c1.z; Bs[kb + 7][smm] = c1.w;
        __syncthreads();

        #pragma unroll
        for (int kk = 0; kk < 16; ++kk) {
            float av[8], bv[8];
            *(float4*)&av[0] = *(const float4*)&As[kk][ty * 8];
            *(float4*)&av[4] = *(const float4*)&As[kk][ty * 8 + 4];
            *(float4*)&bv[0] = *(const float4*)&Bs[kk][tx * 8];
            *(float4*)&bv[4] = *(const float4*)&Bs[kk][tx * 8 + 4];
            #pragma unroll
            for (int r = 0; r < 8; ++r)
                #pragma unroll
                for (int s = 0; s < 8; ++s)
                    acc[r][s] += av[r] * bv[s];
        }
    }

    #pragma unroll
    for (int s = 0; s < 8; ++s) {
        const int j = n0 + tx * 8 + s;
        const float bias = bih[j] + bhh[j];
        #pragma unroll
        for (int r = 0; r < 8; ++r) {
            const int mm = ty * 8 + r;
            const int m = m0 + mm;
            const int tt = m >> 6;
            const int bb = m & 63;
            Xz[(size_t)tt * XZ_TSTRIDE + (size_t)j * 64 + bb] = acc[r][s] + bias;
        }
    }
}

// ---------------------------------------------------------------------------
// Kernel B: persistent recurrence, fence-free producer/consumer protocol.
// Per step: h(t) slice -> hseq[t] via sc0sc1 stores; flag[t][bid] via sc0sc1;
// consumers poll flags with bypass loads (wave 0 only), then stage hseq[t]
// with PLAIN loads (addresses fresh per step -> caches can't be stale).
// ---------------------------------------------------------------------------
__global__ __launch_bounds__(256, 1) void lstm_persist(
    const float* __restrict__ Xz, const float* __restrict__ Whh,
    unsigned short* __restrict__ hseq, int* __restrict__ flags,
    float* __restrict__ outg, float* __restrict__ outf,
    float* __restrict__ outi, float* __restrict__ outo)
{
    __shared__ uint4 Wl4[3072];   // 32 rows x 768 bf16, swizzled  (48 KB)
    __shared__ uint4 Hl4[6144];   // 64 rows x 768 bf16, swizzled  (96 KB)
    __shared__ alignas(16) unsigned short hst[4][16][8];   // 1 KB pack buffer
    char* const Wl = (char*)Wl4;
    char* const Hl = (char*)Hl4;

    const int tid  = threadIdx.x;
    const int lane = tid & 63;
    const int w    = tid >> 6;
    const int bid  = blockIdx.x;
    const int j0   = bid * UB;

    // ---- one-time: W_hh slice -> bf16 -> LDS (swizzled) --------------------
    for (int idx = tid; idx < 3072; idx += 256) {
        const int c  = idx / 96;
        const int kc = (idx % 96) * 8;
        const int R  = (c >> 3) * HID + j0 + (c & 7);
        const float* src = Whh + (size_t)R * HID + kc;
        const float4 f0 = *(const float4*)src;
        const float4 f1 = *(const float4*)(src + 4);
        uint4 pk;
        pk.x = (unsigned)f2bf(f0.x) | ((unsigned)f2bf(f0.y) << 16);
        pk.y = (unsigned)f2bf(f0.z) | ((unsigned)f2bf(f0.w) << 16);
        pk.z = (unsigned)f2bf(f1.x) | ((unsigned)f2bf(f1.y) << 16);
        pk.w = (unsigned)f2bf(f1.z) | ((unsigned)f2bf(f1.w) << 16);
        *(uint4*)(Wl + swz((unsigned)(c * 1536 + kc * 2))) = pk;
    }
    // ---- zero Hl (h(-1) = 0) ----------------------------------------------
    {
        const uint4 zz = {0u, 0u, 0u, 0u};
        for (int idx = tid; idx < 6144; idx += 256) {
            const int row = idx / 96;
            const int kb  = (idx % 96) * 16;
            *(uint4*)(Hl + swz((unsigned)(row * 1536 + kb))) = zz;
        }
    }

    // ---- per-lane constants ------------------------------------------------
    const int col   = lane & 15;
    const int u     = col & 7;
    const int gsel  = col >> 3;
    const int rbase = w * 16 + (lane >> 4) * 4;

    const unsigned kbl   = (unsigned)((lane >> 4) * 16);
    const unsigned aLin  = (unsigned)((w * 16 + col) * 1536) + kbl;
    const unsigned b0Lin = (unsigned)(col * 1536) + kbl;
    const unsigned b1Lin = (unsigned)((16 + col) * 1536) + kbl;

    float* const p0 = gsel ? outf : outi;
    float* const p1 = gsel ? outo : outg;
    const size_t xzR0 = (size_t)(gsel * HID + j0 + u) * 64;
    const size_t xzR1 = (size_t)((2 + gsel) * HID + j0 + u) * 64;

    float cReg[4] = {0.f, 0.f, 0.f, 0.f};

    __syncthreads();

    // Xz prefetch for t=0
    f32x4 xz0 = *(const f32x4*)(Xz + (size_t)rbase + xzR0);
    f32x4 xz1 = *(const f32x4*)(Xz + (size_t)rbase + xzR1);

    for (int t = 0; t < SEQ; ++t) {
        // ---- z_hh = h . Whh^T via MFMA ------------------------------------
        f32x4 acc0 = {0.f, 0.f, 0.f, 0.f};
        f32x4 acc1 = {0.f, 0.f, 0.f, 0.f};
        #pragma unroll 8
        for (int ks = 0; ks < 24; ++ks) {
            const bf16x8 af = *(const bf16x8*)(Hl + swz(aLin + ks * 64));
            const bf16x8 b0 = *(const bf16x8*)(Wl + swz(b0Lin + ks * 64));
            const bf16x8 b1 = *(const bf16x8*)(Wl + swz(b1Lin + ks * 64));
            acc0 = __builtin_amdgcn_mfma_f32_16x16x32_bf16(af, b0, acc0, 0, 0, 0);
            acc1 = __builtin_amdgcn_mfma_f32_16x16x32_bf16(af, b1, acc1, 0, 0, 0);
        }

        // ---- gates --------------------------------------------------------
        float v0[4], v1[4];
        #pragma unroll
        for (int r = 0; r < 4; ++r) {
            const float z0 = acc0[r] + xz0[r];
            const float z1 = acc1[r] + xz1[r];
            v0[r] = sigm(z0);                          // i or f
            v1[r] = gsel ? sigm(z1) : tanh_(z1);       // o or g
        }

        // ---- h/c update; pack h slice into LDS ----------------------------
        #pragma unroll
        for (int r = 0; r < 4; ++r) {
            const float pr0 = __shfl_xor(v0[r], 8);    // f (for gsel==0 lanes)
            const float pr1 = __shfl_xor(v1[r], 8);    // o (for gsel==0 lanes)
            if (gsel == 0) {
                const float cN = pr0 * cReg[r] + v0[r] * v1[r];
                cReg[r] = cN;
                hst[w][(lane >> 4) * 4 + r][u] = f2bf(pr1 * tanh_(cN));
            }
        }

        // ---- publish h slice (write-through to coherence point) -----------
        unsigned short* hT = hseq + (size_t)t * TB_STRIDE;
        if (lane < 16) {
            const u32x4 hv = *(const u32x4*)&hst[w][lane][0];
            store16_sys(hT + (size_t)(w * 16 + lane) * HID + j0, hv);
        }
        asm volatile("s_waitcnt vmcnt(0)" ::: "memory");
        __syncthreads();                                   // all waves' h out
        if (tid == 0) store4_sys(flags + (t << 7) + bid, t + 1);

        // ---- gate stores (plain, off critical path, overlap poll) ---------
        const size_t ob = (size_t)t * TB_STRIDE + (size_t)rbase * HID + (size_t)(j0 + u);
        #pragma unroll
        for (int r = 0; r < 4; ++r) {
            p0[ob + (size_t)r * HID] = v0[r];
            p1[ob + (size_t)r * HID] = v1[r];
        }

        if (t < SEQ - 1) {
            // ---- Xz prefetch for t+1 (HBM latency hides under poll) -------
            const size_t xzb = (size_t)(t + 1) * XZ_TSTRIDE + (size_t)rbase;
            xz0 = *(const f32x4*)(Xz + xzb + xzR0);
            xz1 = *(const f32x4*)(Xz + xzb + xzR1);

            // ---- poll step-t flags (wave 0 only, bypass loads) ------------
            if (w == 0) {
                const int T = t + 1;
                const bool active = lane < 24;
                const int* fp = flags + (t << 7) + (lane << 2);
                while (true) {
                    bool ok = true;
                    if (active) {
                        const u32x4 f = load16_sys(fp);
                        ok = ((int)f[0] >= T) & ((int)f[1] >= T) &
                             ((int)f[2] >= T) & ((int)f[3] >= T);
                    }
                    if (__all(ok)) break;
                    __builtin_amdgcn_s_sleep(1);
                }
            }
            __syncthreads();                               // release block

            // ---- stage h(t) -> LDS via PLAIN loads (fresh addresses) ------
            const unsigned short* hin = hseq + (size_t)t * TB_STRIDE;
            #pragma unroll 8
            for (int it = 0; it < 24; ++it) {
                const int idx = tid + it * 256;
                const int row = idx / 96;
                const int kb  = (idx % 96) * 16;
                const uint4 v = *(const uint4*)(hin + (size_t)idx * 8);
                *(uint4*)(Hl + swz((unsigned)(row * 1536 + kb))) = v;
            }
            __syncthreads();
        }
    }
}

// ---------------------------------------------------------------------------
// Kernel C: logits
// ---------------------------------------------------------------------------
__global__ void logits_k(const unsigned short* __restrict__ hT,
                         const float* __restrict__ Wcls,
                         const float* __restrict__ bcls,
                         float* __restrict__ out)
{
    const int tid = threadIdx.x;          // 128 threads
    const int b = tid >> 1, cls = tid & 1;
    float acc = bcls[cls];
    const unsigned short* __restrict__ hr = hT + b * HID;
    const float* __restrict__ wr = Wcls + cls * HID;
    for (int k = 0; k < HID; ++k) acc += bf2f(hr[k]) * wr[k];
    out[b * 2 + cls] = acc;
}

// ---------------------------------------------------------------------------
extern "C" void kernel_launch(void* const* d_in, const int* in_sizes, int n_in,
                              void* d_out, int out_size, void* d_ws, size_t ws_size,
                              hipStream_t stream)
{
    const int*   tok  = (const int*)d_in[0];
    const float* emb  = (const float*)d_in[1];
    const float* Wih  = (const float*)d_in[2];
    const float* Whh  = (const float*)d_in[3];
    const float* bih  = (const float*)d_in[4];
    const float* bhh  = (const float*)d_in[5];
    const float* Wcls = (const float*)d_in[6];
    const float* bcls = (const float*)d_in[7];
    float* out = (float*)d_out;

    char* ws = (char*)d_ws;
    float* Xz = (float*)ws;                                   // 201,326,592 B
    unsigned short* hseq = (unsigned short*)(ws + HSEQ_OFF);  // 25,165,824 B
    int* flags = (int*)(ws + FLAGS_OFF);                      // 131,072 B

    float* out_log = out;             // [64,2]
    float* out_g = out + 128;
    float* out_f = out_g + GSTRIDE;
    float* out_i = out_f + GSTRIDE;
    float* out_o = out_i + GSTRIDE;

    hipMemsetAsync(flags, 0, FLAGS_BYTES, stream);

    gemm_xz<<<dim3(24, 128), 256, 0, stream>>>(tok, emb, Wih, bih, bhh, Xz);

    lstm_persist<<<NB, 256, 0, stream>>>(Xz, Whh, hseq, flags,
                                         out_g, out_f, out_i, out_o);

    logits_k<<<1, 128, 0, stream>>>(hseq + (size_t)(SEQ - 1) * TB_STRIDE,
                                    Wcls, bcls, out_log);
}